// Round 3
// baseline (1783.260 us; speedup 1.0000x reference)
//
#include <hip/hip_runtime.h>

#define HD 64
#define FC 16
#define FEMB 8

// ---- degree count: integer atomics ----
__global__ void k_deg_count(const int* __restrict__ dst, int* __restrict__ deg, int E) {
    int stride = gridDim.x * blockDim.x;
    for (int i = blockIdx.x * blockDim.x + threadIdx.x; i < E; i += stride)
        atomicAdd(&deg[dst[i]], 1);
}

// ---- scan phase 1: per-block exclusive scan of deg; also compute disq ----
__global__ void k_scan1(const int* __restrict__ deg, int* __restrict__ row_part,
                        int* __restrict__ bsum, float* __restrict__ disq, int n) {
    __shared__ int s[256];
    int t = threadIdx.x;
    int i = blockIdx.x * 256 + t;
    int v = (i < n) ? deg[i] : 0;
    if (i < n) disq[i] = rsqrtf(1.0f + (float)v);
    s[t] = v;
    __syncthreads();
    for (int off = 1; off < 256; off <<= 1) {
        int a = (t >= off) ? s[t - off] : 0;
        __syncthreads();
        s[t] += a;
        __syncthreads();
    }
    if (i < n) row_part[i] = s[t] - v;
    if (t == 255) bsum[blockIdx.x] = s[255];
}

// ---- scan phase 2: exclusive scan of block sums (single block) ----
__global__ void k_scan2(int* __restrict__ bsum, int nb) {
    __shared__ int s[1024];
    int t = threadIdx.x;
    int v = (t < nb) ? bsum[t] : 0;
    s[t] = v;
    __syncthreads();
    for (int off = 1; off < 1024; off <<= 1) {
        int a = (t >= off) ? s[t - off] : 0;
        __syncthreads();
        s[t] += a;
        __syncthreads();
    }
    if (t < nb) bsum[t] = s[t] - v;
}

// ---- scan phase 3: add block offsets; init cursor copy ----
__global__ void k_scan3(int* __restrict__ row_part, const int* __restrict__ bsum,
                        int* __restrict__ cursor, int n) {
    int stride = gridDim.x * blockDim.x;
    for (int i = blockIdx.x * blockDim.x + threadIdx.x; i < n; i += stride) {
        int rs = row_part[i] + bsum[i >> 8];
        row_part[i] = rs;
        cursor[i] = rs;
    }
}

// ---- scatter edges into CSR slots: {src, disq[src]} ----
__global__ void k_scatter(const int* __restrict__ src, const int* __restrict__ dst,
                          const float* __restrict__ disq, int* __restrict__ cursor,
                          int2* __restrict__ csr, int E) {
    int stride = gridDim.x * blockDim.x;
    for (int e = blockIdx.x * blockDim.x + threadIdx.x; e < E; e += stride) {
        int s = src[e], d = dst[e];
        int pos = atomicAdd(&cursor[d], 1);
        csr[pos] = make_int2(s, __float_as_int(disq[s]));
    }
}

// ---- input layer ----
__global__ void k_input(const float* __restrict__ xc, const int* __restrict__ ft,
                        const float* __restrict__ emb, const float* __restrict__ Win,
                        const float* __restrict__ bin, float* __restrict__ x, int n) {
    int lane = threadIdx.x & 63;
    int wid  = (blockIdx.x * blockDim.x + threadIdx.x) >> 6;
    if (wid >= n) return;
    float acc = bin[lane];
    const float* xr = xc + (size_t)wid * FC;
#pragma unroll
    for (int k = 0; k < FC; k++)
        acc = fmaf(xr[k], Win[k * HD + lane], acc);
    int t = ft[wid];
    const float* er = emb + (size_t)t * FEMB;
#pragma unroll
    for (int k = 0; k < FEMB; k++)
        acc = fmaf(er[k], Win[(FC + k) * HD + lane], acc);
    x[(size_t)wid * HD + lane] = fmaxf(acc, 0.0f);
}

// ---- aggregation: one wave per node, 4-way unrolled gather (MLP) ----
__global__ void k_agg(const float* __restrict__ x, const int2* __restrict__ csr,
                      const int* __restrict__ rs, const int* __restrict__ deg,
                      const float* __restrict__ disq, float* __restrict__ agg, int n) {
    int lane = threadIdx.x & 63;
    int node = (blockIdx.x * blockDim.x + threadIdx.x) >> 6;
    if (node >= n) return;
    int j   = rs[node];
    int end = j + deg[node];
    float di = disq[node];
    float a0 = 0.f, a1 = 0.f, a2 = 0.f, a3 = 0.f;
    for (; j + 4 <= end; j += 4) {
        int2 e0 = csr[j], e1 = csr[j + 1], e2 = csr[j + 2], e3 = csr[j + 3];
        a0 = fmaf(__int_as_float(e0.y), x[(size_t)e0.x * HD + lane], a0);
        a1 = fmaf(__int_as_float(e1.y), x[(size_t)e1.x * HD + lane], a1);
        a2 = fmaf(__int_as_float(e2.y), x[(size_t)e2.x * HD + lane], a2);
        a3 = fmaf(__int_as_float(e3.y), x[(size_t)e3.x * HD + lane], a3);
    }
    for (; j < end; j++) {
        int2 e = csr[j];
        a0 = fmaf(__int_as_float(e.y), x[(size_t)e.x * HD + lane], a0);
    }
    float acc = (a0 + a1) + (a2 + a3);
    agg[(size_t)node * HD + lane] = fmaf(di, acc, di * di * x[(size_t)node * HD + lane]);
}

// ---- tiled matmul + bias + relu, IN PLACE: x[tile] = relu(x[tile] @ W + b) ----
// block = 256 threads, tile = 64 nodes x 64 cols, 4x4 register tile per thread
__global__ void k_mm(float* __restrict__ x, const float* __restrict__ W,
                     const float* __restrict__ b, int n) {
    __shared__ float xs[64][68];  // +4 pad: bank = (nn*68+k)%32 spreads over nn
    __shared__ float ws[64][64];  // ws[k][c]; lanes read consecutive c -> 2-way max
    int tid = threadIdx.x;
    int node0 = blockIdx.x * 64;

#pragma unroll
    for (int i = tid; i < 64 * 16; i += 256) {  // W: 1024 float4
        int k = i >> 4, c4 = i & 15;
        float4 v = ((const float4*)W)[i];
        ws[k][c4 * 4 + 0] = v.x; ws[k][c4 * 4 + 1] = v.y;
        ws[k][c4 * 4 + 2] = v.z; ws[k][c4 * 4 + 3] = v.w;
    }
#pragma unroll
    for (int i = tid; i < 64 * 16; i += 256) {  // x tile
        int nn = i >> 4, k4 = i & 15;
        int row = node0 + nn; if (row >= n) row = n - 1;  // clamp (stores guarded)
        float4 v = ((const float4*)(x + (size_t)row * HD))[k4];
        xs[nn][k4 * 4 + 0] = v.x; xs[nn][k4 * 4 + 1] = v.y;
        xs[nn][k4 * 4 + 2] = v.z; xs[nn][k4 * 4 + 3] = v.w;
    }
    __syncthreads();

    int tc = (tid & 15) * 4;   // col group
    int tn = (tid >> 4) * 4;   // node group
    float acc[4][4] = {};
#pragma unroll
    for (int k = 0; k < 64; k++) {
        float w0 = ws[k][tc + 0], w1 = ws[k][tc + 1];
        float w2 = ws[k][tc + 2], w3 = ws[k][tc + 3];
        float x0 = xs[tn + 0][k], x1 = xs[tn + 1][k];
        float x2 = xs[tn + 2][k], x3 = xs[tn + 3][k];
        acc[0][0] = fmaf(x0, w0, acc[0][0]); acc[0][1] = fmaf(x0, w1, acc[0][1]);
        acc[0][2] = fmaf(x0, w2, acc[0][2]); acc[0][3] = fmaf(x0, w3, acc[0][3]);
        acc[1][0] = fmaf(x1, w0, acc[1][0]); acc[1][1] = fmaf(x1, w1, acc[1][1]);
        acc[1][2] = fmaf(x1, w2, acc[1][2]); acc[1][3] = fmaf(x1, w3, acc[1][3]);
        acc[2][0] = fmaf(x2, w0, acc[2][0]); acc[2][1] = fmaf(x2, w1, acc[2][1]);
        acc[2][2] = fmaf(x2, w2, acc[2][2]); acc[2][3] = fmaf(x2, w3, acc[2][3]);
        acc[3][0] = fmaf(x3, w0, acc[3][0]); acc[3][1] = fmaf(x3, w1, acc[3][1]);
        acc[3][2] = fmaf(x3, w2, acc[3][2]); acc[3][3] = fmaf(x3, w3, acc[3][3]);
    }

    float b0 = b[tc + 0], b1 = b[tc + 1], b2 = b[tc + 2], b3 = b[tc + 3];
#pragma unroll
    for (int i = 0; i < 4; i++) {
        int row = node0 + tn + i;
        if (row < n) {
            float4 o;
            o.x = fmaxf(acc[i][0] + b0, 0.0f);
            o.y = fmaxf(acc[i][1] + b1, 0.0f);
            o.z = fmaxf(acc[i][2] + b2, 0.0f);
            o.w = fmaxf(acc[i][3] + b3, 0.0f);
            *(float4*)(x + (size_t)row * HD + tc) = o;
        }
    }
}

// ---- head ----
__global__ void k_head(const float* __restrict__ x, const float* __restrict__ W1,
                       const float* __restrict__ b1, const float* __restrict__ W2,
                       const float* __restrict__ b2, float* __restrict__ out, int n) {
    int lane = threadIdx.x & 63;
    int wid  = (blockIdx.x * blockDim.x + threadIdx.x) >> 6;
    if (wid >= n) return;
    float w2  = W2[lane];
    float b2v = b2[0];
    const float4* xr = (const float4*)(x + (size_t)wid * HD);
    float acc = b1[lane];
#pragma unroll
    for (int k4 = 0; k4 < HD / 4; k4++) {
        float4 v = xr[k4];
        acc = fmaf(v.x, W1[(k4 * 4 + 0) * HD + lane], acc);
        acc = fmaf(v.y, W1[(k4 * 4 + 1) * HD + lane], acc);
        acc = fmaf(v.z, W1[(k4 * 4 + 2) * HD + lane], acc);
        acc = fmaf(v.w, W1[(k4 * 4 + 3) * HD + lane], acc);
    }
    float pp = fmaxf(acc, 0.0f) * w2;
#pragma unroll
    for (int off = 32; off > 0; off >>= 1)
        pp += __shfl_xor(pp, off);
    if (lane == 0) out[wid] = pp + b2v;
}

extern "C" void kernel_launch(void* const* d_in, const int* in_sizes, int n_in,
                              void* d_out, int out_size, void* d_ws, size_t ws_size,
                              hipStream_t stream) {
    const float* x_cont = (const float*)d_in[0];
    const int*   ftyp   = (const int*)d_in[1];
    const int*   eidx   = (const int*)d_in[2];
    const float* emb    = (const float*)d_in[3];
    const float* W_in   = (const float*)d_in[4];
    const float* b_in   = (const float*)d_in[5];
    const float* W_g    = (const float*)d_in[6];
    const float* b_g    = (const float*)d_in[7];
    const float* W_o1   = (const float*)d_in[8];
    const float* b_o1   = (const float*)d_in[9];
    const float* W_o2   = (const float*)d_in[10];
    const float* b_o2   = (const float*)d_in[11];
    float* out = (float*)d_out;

    const int n = in_sizes[1];
    const int E = in_sizes[2] / 2;
    const int* src = eidx;
    const int* dst = eidx + E;

    char* p = (char*)d_ws;
    auto alloc = [&](size_t bytes) {
        char* r = p;
        p += (bytes + 255) & ~(size_t)255;
        return r;
    };
    int*   deg    = (int*)  alloc((size_t)n * 4);
    float* disq   = (float*)alloc((size_t)n * 4);
    int*   rowst  = (int*)  alloc((size_t)n * 4);
    int*   cursor = (int*)  alloc((size_t)n * 4);
    int*   bsum   = (int*)  alloc(4096);
    int2*  csr    = (int2*) alloc((size_t)E * 8);
    float* xb     = (float*)alloc((size_t)n * HD * 4);
    float* xo     = (float*)alloc((size_t)n * HD * 4);

    hipMemsetAsync(deg, 0, (size_t)n * 4, stream);

    dim3 blk(256);
    const int nb1   = (n + 255) / 256;
    const int nb_e  = 2048;
    const int nb_nw = (n + 3) / 4;       // one wave per node (blocks of 4 waves)
    const int nb_t  = (n + 63) / 64;     // 64-node tiles

    k_deg_count<<<nb_e, blk, 0, stream>>>(dst, deg, E);
    k_scan1<<<nb1, blk, 0, stream>>>(deg, rowst, bsum, disq, n);
    k_scan2<<<1, 1024, 0, stream>>>(bsum, nb1);
    k_scan3<<<512, blk, 0, stream>>>(rowst, bsum, cursor, n);
    k_scatter<<<nb_e, blk, 0, stream>>>(src, dst, disq, cursor, csr, E);
    k_input<<<nb_nw, blk, 0, stream>>>(x_cont, ftyp, emb, W_in, b_in, xb, n);

    float* a = xb;
    float* bpp = xo;
    for (int L = 0; L < 3; L++) {
        k_agg<<<nb_nw, blk, 0, stream>>>(a, csr, rowst, deg, disq, bpp, n);
        k_mm<<<nb_t, blk, 0, stream>>>(bpp, W_g + (size_t)L * HD * HD,
                                       b_g + (size_t)L * HD, n);
        float* t = a; a = bpp; bpp = t;
    }

    k_head<<<nb_nw, blk, 0, stream>>>(a, W_o1, b_o1, W_o2, b_o2, out, n);
}

// Round 4
// 504.165 us; speedup vs baseline: 3.5371x; 3.5371x over previous
//
#include <hip/hip_runtime.h>

#define HD 64
#define FC 16
#define FEMB 8

// ---- degree count: integer atomics ----
__global__ void k_deg_count(const int* __restrict__ dst, int* __restrict__ deg, int E) {
    int stride = gridDim.x * blockDim.x;
    for (int i = blockIdx.x * blockDim.x + threadIdx.x; i < E; i += stride)
        atomicAdd(&deg[dst[i]], 1);
}

// ---- scan phase 1: per-block exclusive scan of deg; also compute disq ----
__global__ void k_scan1(const int* __restrict__ deg, int* __restrict__ row_part,
                        int* __restrict__ bsum, float* __restrict__ disq, int n) {
    __shared__ int s[256];
    int t = threadIdx.x;
    int i = blockIdx.x * 256 + t;
    int v = (i < n) ? deg[i] : 0;
    if (i < n) disq[i] = rsqrtf(1.0f + (float)v);
    s[t] = v;
    __syncthreads();
    for (int off = 1; off < 256; off <<= 1) {
        int a = (t >= off) ? s[t - off] : 0;
        __syncthreads();
        s[t] += a;
        __syncthreads();
    }
    if (i < n) row_part[i] = s[t] - v;
    if (t == 255) bsum[blockIdx.x] = s[255];
}

// ---- scan phase 2: exclusive scan of block sums (single block) ----
__global__ void k_scan2(int* __restrict__ bsum, int nb) {
    __shared__ int s[1024];
    int t = threadIdx.x;
    int v = (t < nb) ? bsum[t] : 0;
    s[t] = v;
    __syncthreads();
    for (int off = 1; off < 1024; off <<= 1) {
        int a = (t >= off) ? s[t - off] : 0;
        __syncthreads();
        s[t] += a;
        __syncthreads();
    }
    if (t < nb) bsum[t] = s[t] - v;
}

// ---- scan phase 3: add block offsets; init cursor copy ----
__global__ void k_scan3(int* __restrict__ row_part, const int* __restrict__ bsum,
                        int* __restrict__ cursor, int n) {
    int stride = gridDim.x * blockDim.x;
    for (int i = blockIdx.x * blockDim.x + threadIdx.x; i < n; i += stride) {
        int rs = row_part[i] + bsum[i >> 8];
        row_part[i] = rs;
        cursor[i] = rs;
    }
}

// ---- scatter edges into CSR slots: {src, disq[src]} ----
__global__ void k_scatter(const int* __restrict__ src, const int* __restrict__ dst,
                          const float* __restrict__ disq, int* __restrict__ cursor,
                          int2* __restrict__ csr, int E) {
    int stride = gridDim.x * blockDim.x;
    for (int e = blockIdx.x * blockDim.x + threadIdx.x; e < E; e += stride) {
        int s = src[e], d = dst[e];
        int pos = atomicAdd(&cursor[d], 1);
        csr[pos] = make_int2(s, __float_as_int(disq[s]));
    }
}

// ---- input layer ----
__global__ void k_input(const float* __restrict__ xc, const int* __restrict__ ft,
                        const float* __restrict__ emb, const float* __restrict__ Win,
                        const float* __restrict__ bin, float* __restrict__ x, int n) {
    int lane = threadIdx.x & 63;
    int wid  = (blockIdx.x * blockDim.x + threadIdx.x) >> 6;
    if (wid >= n) return;
    float acc = bin[lane];
    const float* xr = xc + (size_t)wid * FC;
#pragma unroll
    for (int k = 0; k < FC; k++)
        acc = fmaf(xr[k], Win[k * HD + lane], acc);
    int t = ft[wid];
    const float* er = emb + (size_t)t * FEMB;
#pragma unroll
    for (int k = 0; k < FEMB; k++)
        acc = fmaf(er[k], Win[(FC + k) * HD + lane], acc);
    x[(size_t)wid * HD + lane] = fmaxf(acc, 0.0f);
}

// ---- aggregation: one wave per node, 4-way unrolled gather (MLP) ----
__global__ void k_agg(const float* __restrict__ x, const int2* __restrict__ csr,
                      const int* __restrict__ rs, const int* __restrict__ deg,
                      const float* __restrict__ disq, float* __restrict__ agg, int n) {
    int lane = threadIdx.x & 63;
    int node = (blockIdx.x * blockDim.x + threadIdx.x) >> 6;
    if (node >= n) return;
    int j   = rs[node];
    int end = j + deg[node];
    float di = disq[node];
    float a0 = 0.f, a1 = 0.f, a2 = 0.f, a3 = 0.f;
    for (; j + 4 <= end; j += 4) {
        int2 e0 = csr[j], e1 = csr[j + 1], e2 = csr[j + 2], e3 = csr[j + 3];
        a0 = fmaf(__int_as_float(e0.y), x[(size_t)e0.x * HD + lane], a0);
        a1 = fmaf(__int_as_float(e1.y), x[(size_t)e1.x * HD + lane], a1);
        a2 = fmaf(__int_as_float(e2.y), x[(size_t)e2.x * HD + lane], a2);
        a3 = fmaf(__int_as_float(e3.y), x[(size_t)e3.x * HD + lane], a3);
    }
    for (; j < end; j++) {
        int2 e = csr[j];
        a0 = fmaf(__int_as_float(e.y), x[(size_t)e.x * HD + lane], a0);
    }
    float acc = (a0 + a1) + (a2 + a3);
    agg[(size_t)node * HD + lane] = fmaf(di, acc, di * di * x[(size_t)node * HD + lane]);
}

// ---- tiled matmul + bias + relu, IN PLACE: x[tile] = relu(x[tile] @ W + b) ----
// block = 256 threads, tile = 64 nodes x 64 cols, 4 nodes x 4 cols per thread.
// All LDS traffic is ds_read_b128; acc is 4 float4 -> ~60 live VGPRs, no spill.
__global__ __launch_bounds__(256, 4)
void k_mm(float* __restrict__ x, const float* __restrict__ W,
          const float* __restrict__ b, int n) {
    __shared__ float4 ws4[64][16];  // ws4[k][c4] = W[k][4*c4 .. 4*c4+3]
    __shared__ float4 xs4[64][17];  // xs4[nn][k4], pad 17 -> row stride 68 words
    int tid = threadIdx.x;
    int node0 = blockIdx.x * 64;

    for (int i = tid; i < 1024; i += 256)
        ws4[i >> 4][i & 15] = ((const float4*)W)[i];
    for (int i = tid; i < 1024; i += 256) {
        int nn = i >> 4, k4 = i & 15;
        int row = node0 + nn; if (row >= n) row = n - 1;  // stores guarded below
        xs4[nn][k4] = ((const float4*)(x + (size_t)row * HD))[k4];
    }
    __syncthreads();

    int tc4 = tid & 15;          // float4 col group
    int tn  = (tid >> 4) * 4;    // node group
    float4 ac0 = {0,0,0,0}, ac1 = {0,0,0,0}, ac2 = {0,0,0,0}, ac3 = {0,0,0,0};

#pragma unroll 4
    for (int k4 = 0; k4 < 16; k4++) {
        float4 w0 = ws4[k4 * 4 + 0][tc4];
        float4 w1 = ws4[k4 * 4 + 1][tc4];
        float4 w2 = ws4[k4 * 4 + 2][tc4];
        float4 w3 = ws4[k4 * 4 + 3][tc4];
#pragma unroll
        for (int i = 0; i < 4; i++) {
            float4 xv = xs4[tn + i][k4];
            float4* ac = (i == 0) ? &ac0 : (i == 1) ? &ac1 : (i == 2) ? &ac2 : &ac3;
            ac->x = fmaf(xv.x, w0.x, ac->x); ac->y = fmaf(xv.x, w0.y, ac->y);
            ac->z = fmaf(xv.x, w0.z, ac->z); ac->w = fmaf(xv.x, w0.w, ac->w);
            ac->x = fmaf(xv.y, w1.x, ac->x); ac->y = fmaf(xv.y, w1.y, ac->y);
            ac->z = fmaf(xv.y, w1.z, ac->z); ac->w = fmaf(xv.y, w1.w, ac->w);
            ac->x = fmaf(xv.z, w2.x, ac->x); ac->y = fmaf(xv.z, w2.y, ac->y);
            ac->z = fmaf(xv.z, w2.z, ac->z); ac->w = fmaf(xv.z, w2.w, ac->w);
            ac->x = fmaf(xv.w, w3.x, ac->x); ac->y = fmaf(xv.w, w3.y, ac->y);
            ac->z = fmaf(xv.w, w3.z, ac->z); ac->w = fmaf(xv.w, w3.w, ac->w);
        }
    }

    float4 bb = ((const float4*)b)[tc4];
    float4 accs[4] = {ac0, ac1, ac2, ac3};
#pragma unroll
    for (int i = 0; i < 4; i++) {
        int row = node0 + tn + i;
        if (row < n) {
            float4 o;
            o.x = fmaxf(accs[i].x + bb.x, 0.0f);
            o.y = fmaxf(accs[i].y + bb.y, 0.0f);
            o.z = fmaxf(accs[i].z + bb.z, 0.0f);
            o.w = fmaxf(accs[i].w + bb.w, 0.0f);
            *(float4*)(x + (size_t)row * HD + tc4 * 4) = o;
        }
    }
}

// ---- head ----
__global__ void k_head(const float* __restrict__ x, const float* __restrict__ W1,
                       const float* __restrict__ b1, const float* __restrict__ W2,
                       const float* __restrict__ b2, float* __restrict__ out, int n) {
    int lane = threadIdx.x & 63;
    int wid  = (blockIdx.x * blockDim.x + threadIdx.x) >> 6;
    if (wid >= n) return;
    float w2  = W2[lane];
    float b2v = b2[0];
    const float4* xr = (const float4*)(x + (size_t)wid * HD);
    float acc = b1[lane];
#pragma unroll
    for (int k4 = 0; k4 < HD / 4; k4++) {
        float4 v = xr[k4];
        acc = fmaf(v.x, W1[(k4 * 4 + 0) * HD + lane], acc);
        acc = fmaf(v.y, W1[(k4 * 4 + 1) * HD + lane], acc);
        acc = fmaf(v.z, W1[(k4 * 4 + 2) * HD + lane], acc);
        acc = fmaf(v.w, W1[(k4 * 4 + 3) * HD + lane], acc);
    }
    float pp = fmaxf(acc, 0.0f) * w2;
#pragma unroll
    for (int off = 32; off > 0; off >>= 1)
        pp += __shfl_xor(pp, off);
    if (lane == 0) out[wid] = pp + b2v;
}

extern "C" void kernel_launch(void* const* d_in, const int* in_sizes, int n_in,
                              void* d_out, int out_size, void* d_ws, size_t ws_size,
                              hipStream_t stream) {
    const float* x_cont = (const float*)d_in[0];
    const int*   ftyp   = (const int*)d_in[1];
    const int*   eidx   = (const int*)d_in[2];
    const float* emb    = (const float*)d_in[3];
    const float* W_in   = (const float*)d_in[4];
    const float* b_in   = (const float*)d_in[5];
    const float* W_g    = (const float*)d_in[6];
    const float* b_g    = (const float*)d_in[7];
    const float* W_o1   = (const float*)d_in[8];
    const float* b_o1   = (const float*)d_in[9];
    const float* W_o2   = (const float*)d_in[10];
    const float* b_o2   = (const float*)d_in[11];
    float* out = (float*)d_out;

    const int n = in_sizes[1];
    const int E = in_sizes[2] / 2;
    const int* src = eidx;
    const int* dst = eidx + E;

    char* p = (char*)d_ws;
    auto alloc = [&](size_t bytes) {
        char* r = p;
        p += (bytes + 255) & ~(size_t)255;
        return r;
    };
    int*   deg    = (int*)  alloc((size_t)n * 4);
    float* disq   = (float*)alloc((size_t)n * 4);
    int*   rowst  = (int*)  alloc((size_t)n * 4);
    int*   cursor = (int*)  alloc((size_t)n * 4);
    int*   bsum   = (int*)  alloc(4096);
    int2*  csr    = (int2*) alloc((size_t)E * 8);
    float* xb     = (float*)alloc((size_t)n * HD * 4);
    float* xo     = (float*)alloc((size_t)n * HD * 4);

    hipMemsetAsync(deg, 0, (size_t)n * 4, stream);

    dim3 blk(256);
    const int nb1   = (n + 255) / 256;
    const int nb_e  = 2048;
    const int nb_nw = (n + 3) / 4;       // one wave per node
    const int nb_t  = (n + 63) / 64;     // 64-node tiles

    k_deg_count<<<nb_e, blk, 0, stream>>>(dst, deg, E);
    k_scan1<<<nb1, blk, 0, stream>>>(deg, rowst, bsum, disq, n);
    k_scan2<<<1, 1024, 0, stream>>>(bsum, nb1);
    k_scan3<<<512, blk, 0, stream>>>(rowst, bsum, cursor, n);
    k_scatter<<<nb_e, blk, 0, stream>>>(src, dst, disq, cursor, csr, E);
    k_input<<<nb_nw, blk, 0, stream>>>(x_cont, ftyp, emb, W_in, b_in, xb, n);

    float* a = xb;
    float* bpp = xo;
    for (int L = 0; L < 3; L++) {
        k_agg<<<nb_nw, blk, 0, stream>>>(a, csr, rowst, deg, disq, bpp, n);
        k_mm<<<nb_t, blk, 0, stream>>>(bpp, W_g + (size_t)L * HD * HD,
                                       b_g + (size_t)L * HD, n);
        float* t = a; a = bpp; bpp = t;
    }

    k_head<<<nb_nw, blk, 0, stream>>>(a, W_o1, b_o1, W_o2, b_o2, out, n);
}

// Round 5
// 435.342 us; speedup vs baseline: 4.0962x; 1.1581x over previous
//
#include <hip/hip_runtime.h>

#define HD 64
#define FC 16
#define FEMB 8

// ---- degree count: integer atomics ----
__global__ void k_deg_count(const int* __restrict__ dst, int* __restrict__ deg, int E) {
    int stride = gridDim.x * blockDim.x;
    for (int i = blockIdx.x * blockDim.x + threadIdx.x; i < E; i += stride)
        atomicAdd(&deg[dst[i]], 1);
}

// ---- scan phase 1: per-block exclusive scan of deg; also compute disq ----
__global__ void k_scan1(const int* __restrict__ deg, int* __restrict__ row_part,
                        int* __restrict__ bsum, float* __restrict__ disq, int n) {
    __shared__ int s[256];
    int t = threadIdx.x;
    int i = blockIdx.x * 256 + t;
    int v = (i < n) ? deg[i] : 0;
    if (i < n) disq[i] = rsqrtf(1.0f + (float)v);
    s[t] = v;
    __syncthreads();
    for (int off = 1; off < 256; off <<= 1) {
        int a = (t >= off) ? s[t - off] : 0;
        __syncthreads();
        s[t] += a;
        __syncthreads();
    }
    if (i < n) row_part[i] = s[t] - v;
    if (t == 255) bsum[blockIdx.x] = s[255];
}

// ---- scan phase 2: exclusive scan of block sums (single block) ----
__global__ void k_scan2(int* __restrict__ bsum, int nb) {
    __shared__ int s[1024];
    int t = threadIdx.x;
    int v = (t < nb) ? bsum[t] : 0;
    s[t] = v;
    __syncthreads();
    for (int off = 1; off < 1024; off <<= 1) {
        int a = (t >= off) ? s[t - off] : 0;
        __syncthreads();
        s[t] += a;
        __syncthreads();
    }
    if (t < nb) bsum[t] = s[t] - v;
}

// ---- scan phase 3: add block offsets; init cursor copy ----
__global__ void k_scan3(int* __restrict__ row_part, const int* __restrict__ bsum,
                        int* __restrict__ cursor, int n) {
    int stride = gridDim.x * blockDim.x;
    for (int i = blockIdx.x * blockDim.x + threadIdx.x; i < n; i += stride) {
        int rs = row_part[i] + bsum[i >> 8];
        row_part[i] = rs;
        cursor[i] = rs;
    }
}

// ---- scatter edges into CSR slots: {src, disq[src]} ----
__global__ void k_scatter(const int* __restrict__ src, const int* __restrict__ dst,
                          const float* __restrict__ disq, int* __restrict__ cursor,
                          int2* __restrict__ csr, int E) {
    int stride = gridDim.x * blockDim.x;
    for (int e = blockIdx.x * blockDim.x + threadIdx.x; e < E; e += stride) {
        int s = src[e], d = dst[e];
        int pos = atomicAdd(&cursor[d], 1);
        csr[pos] = make_int2(s, __float_as_int(disq[s]));
    }
}

// ---- input layer ----
__global__ void k_input(const float* __restrict__ xc, const int* __restrict__ ft,
                        const float* __restrict__ emb, const float* __restrict__ Win,
                        const float* __restrict__ bin, float* __restrict__ x, int n) {
    int lane = threadIdx.x & 63;
    int wid  = (blockIdx.x * blockDim.x + threadIdx.x) >> 6;
    if (wid >= n) return;
    float acc = bin[lane];
    const float* xr = xc + (size_t)wid * FC;
#pragma unroll
    for (int k = 0; k < FC; k++)
        acc = fmaf(xr[k], Win[k * HD + lane], acc);
    int t = ft[wid];
    const float* er = emb + (size_t)t * FEMB;
#pragma unroll
    for (int k = 0; k < FEMB; k++)
        acc = fmaf(er[k], Win[(FC + k) * HD + lane], acc);
    x[(size_t)wid * HD + lane] = fmaxf(acc, 0.0f);
}

// ---- aggregation: one wave per node, masked 8-wide gather rounds (MLP) ----
__global__ void k_agg(const float* __restrict__ x, const int2* __restrict__ csr,
                      const int* __restrict__ rs, const int* __restrict__ deg,
                      const float* __restrict__ disq, float* __restrict__ agg, int n) {
    int lane = threadIdx.x & 63;
    int node = (blockIdx.x * blockDim.x + threadIdx.x) >> 6;
    if (node >= n) return;
    int j   = rs[node];
    int end = j + deg[node];
    float di = disq[node];
    float a0 = 0.f, a1 = 0.f, a2 = 0.f, a3 = 0.f;
    float a4 = 0.f, a5 = 0.f, a6 = 0.f, a7 = 0.f;
    for (; j < end; j += 8) {
        // 8 clamped loads in flight; OOB lanes contribute weight 0
        int i0 = j,     i1 = j + 1, i2 = j + 2, i3 = j + 3;
        int i4 = j + 4, i5 = j + 5, i6 = j + 6, i7 = j + 7;
        int2 e0 = csr[i0 < end ? i0 : end - 1];
        int2 e1 = csr[i1 < end ? i1 : end - 1];
        int2 e2 = csr[i2 < end ? i2 : end - 1];
        int2 e3 = csr[i3 < end ? i3 : end - 1];
        int2 e4 = csr[i4 < end ? i4 : end - 1];
        int2 e5 = csr[i5 < end ? i5 : end - 1];
        int2 e6 = csr[i6 < end ? i6 : end - 1];
        int2 e7 = csr[i7 < end ? i7 : end - 1];
        float w0 = i0 < end ? __int_as_float(e0.y) : 0.f;
        float w1 = i1 < end ? __int_as_float(e1.y) : 0.f;
        float w2 = i2 < end ? __int_as_float(e2.y) : 0.f;
        float w3 = i3 < end ? __int_as_float(e3.y) : 0.f;
        float w4 = i4 < end ? __int_as_float(e4.y) : 0.f;
        float w5 = i5 < end ? __int_as_float(e5.y) : 0.f;
        float w6 = i6 < end ? __int_as_float(e6.y) : 0.f;
        float w7 = i7 < end ? __int_as_float(e7.y) : 0.f;
        a0 = fmaf(w0, x[(size_t)e0.x * HD + lane], a0);
        a1 = fmaf(w1, x[(size_t)e1.x * HD + lane], a1);
        a2 = fmaf(w2, x[(size_t)e2.x * HD + lane], a2);
        a3 = fmaf(w3, x[(size_t)e3.x * HD + lane], a3);
        a4 = fmaf(w4, x[(size_t)e4.x * HD + lane], a4);
        a5 = fmaf(w5, x[(size_t)e5.x * HD + lane], a5);
        a6 = fmaf(w6, x[(size_t)e6.x * HD + lane], a6);
        a7 = fmaf(w7, x[(size_t)e7.x * HD + lane], a7);
    }
    float acc = ((a0 + a1) + (a2 + a3)) + ((a4 + a5) + (a6 + a7));
    agg[(size_t)node * HD + lane] = fmaf(di, acc, di * di * x[(size_t)node * HD + lane]);
}

// ---- tiled matmul + bias + relu, IN PLACE: x[tile] = relu(x[tile] @ W + b) ----
__global__ __launch_bounds__(256, 4)
void k_mm(float* __restrict__ x, const float* __restrict__ W,
          const float* __restrict__ b, int n) {
    __shared__ float4 ws4[64][16];  // ws4[k][c4]
    __shared__ float4 xs4[64][17];  // xs4[nn][k4], padded
    int tid = threadIdx.x;
    int node0 = blockIdx.x * 64;

    for (int i = tid; i < 1024; i += 256)
        ws4[i >> 4][i & 15] = ((const float4*)W)[i];
    for (int i = tid; i < 1024; i += 256) {
        int nn = i >> 4, k4 = i & 15;
        int row = node0 + nn; if (row >= n) row = n - 1;
        xs4[nn][k4] = ((const float4*)(x + (size_t)row * HD))[k4];
    }
    __syncthreads();

    int tc4 = tid & 15;
    int tn  = (tid >> 4) * 4;
    float4 ac0 = {0,0,0,0}, ac1 = {0,0,0,0}, ac2 = {0,0,0,0}, ac3 = {0,0,0,0};

#pragma unroll 4
    for (int k4 = 0; k4 < 16; k4++) {
        float4 w0 = ws4[k4 * 4 + 0][tc4];
        float4 w1 = ws4[k4 * 4 + 1][tc4];
        float4 w2 = ws4[k4 * 4 + 2][tc4];
        float4 w3 = ws4[k4 * 4 + 3][tc4];
#pragma unroll
        for (int i = 0; i < 4; i++) {
            float4 xv = xs4[tn + i][k4];
            float4* ac = (i == 0) ? &ac0 : (i == 1) ? &ac1 : (i == 2) ? &ac2 : &ac3;
            ac->x = fmaf(xv.x, w0.x, ac->x); ac->y = fmaf(xv.x, w0.y, ac->y);
            ac->z = fmaf(xv.x, w0.z, ac->z); ac->w = fmaf(xv.x, w0.w, ac->w);
            ac->x = fmaf(xv.y, w1.x, ac->x); ac->y = fmaf(xv.y, w1.y, ac->y);
            ac->z = fmaf(xv.y, w1.z, ac->z); ac->w = fmaf(xv.y, w1.w, ac->w);
            ac->x = fmaf(xv.z, w2.x, ac->x); ac->y = fmaf(xv.z, w2.y, ac->y);
            ac->z = fmaf(xv.z, w2.z, ac->z); ac->w = fmaf(xv.z, w2.w, ac->w);
            ac->x = fmaf(xv.w, w3.x, ac->x); ac->y = fmaf(xv.w, w3.y, ac->y);
            ac->z = fmaf(xv.w, w3.z, ac->z); ac->w = fmaf(xv.w, w3.w, ac->w);
        }
    }

    float4 bb = ((const float4*)b)[tc4];
    float4 accs[4] = {ac0, ac1, ac2, ac3};
#pragma unroll
    for (int i = 0; i < 4; i++) {
        int row = node0 + tn + i;
        if (row < n) {
            float4 o;
            o.x = fmaxf(accs[i].x + bb.x, 0.0f);
            o.y = fmaxf(accs[i].y + bb.y, 0.0f);
            o.z = fmaxf(accs[i].z + bb.z, 0.0f);
            o.w = fmaxf(accs[i].w + bb.w, 0.0f);
            *(float4*)(x + (size_t)row * HD + tc4 * 4) = o;
        }
    }
}

// ---- fused layer-3 matmul + head:
//      h3 = relu(agg @ W + b); h4 = relu(h3 @ W1 + b1); out = h4 @ W2 + b2 ----
__global__ __launch_bounds__(256, 4)
void k_mm_head(const float* __restrict__ x, const float* __restrict__ W,
               const float* __restrict__ b, const float* __restrict__ W1,
               const float* __restrict__ b1, const float* __restrict__ W2,
               const float* __restrict__ b2, float* __restrict__ out, int n) {
    __shared__ float4 ws4[64][16];
    __shared__ float4 xs4[64][17];
    int tid = threadIdx.x;
    int node0 = blockIdx.x * 64;

    for (int i = tid; i < 1024; i += 256)
        ws4[i >> 4][i & 15] = ((const float4*)W)[i];
    for (int i = tid; i < 1024; i += 256) {
        int nn = i >> 4, k4 = i & 15;
        int row = node0 + nn; if (row >= n) row = n - 1;
        xs4[nn][k4] = ((const float4*)(x + (size_t)row * HD))[k4];
    }
    __syncthreads();

    int tc4 = tid & 15;
    int tn  = (tid >> 4) * 4;

    // ---- stage 1: h3 tile ----
    float4 ac0 = {0,0,0,0}, ac1 = {0,0,0,0}, ac2 = {0,0,0,0}, ac3 = {0,0,0,0};
#pragma unroll 4
    for (int k4 = 0; k4 < 16; k4++) {
        float4 w0 = ws4[k4 * 4 + 0][tc4];
        float4 w1 = ws4[k4 * 4 + 1][tc4];
        float4 w2 = ws4[k4 * 4 + 2][tc4];
        float4 w3 = ws4[k4 * 4 + 3][tc4];
#pragma unroll
        for (int i = 0; i < 4; i++) {
            float4 xv = xs4[tn + i][k4];
            float4* ac = (i == 0) ? &ac0 : (i == 1) ? &ac1 : (i == 2) ? &ac2 : &ac3;
            ac->x = fmaf(xv.x, w0.x, ac->x); ac->y = fmaf(xv.x, w0.y, ac->y);
            ac->z = fmaf(xv.x, w0.z, ac->z); ac->w = fmaf(xv.x, w0.w, ac->w);
            ac->x = fmaf(xv.y, w1.x, ac->x); ac->y = fmaf(xv.y, w1.y, ac->y);
            ac->z = fmaf(xv.y, w1.z, ac->z); ac->w = fmaf(xv.y, w1.w, ac->w);
            ac->x = fmaf(xv.z, w2.x, ac->x); ac->y = fmaf(xv.z, w2.y, ac->y);
            ac->z = fmaf(xv.z, w2.z, ac->z); ac->w = fmaf(xv.z, w2.w, ac->w);
            ac->x = fmaf(xv.w, w3.x, ac->x); ac->y = fmaf(xv.w, w3.y, ac->y);
            ac->z = fmaf(xv.w, w3.z, ac->z); ac->w = fmaf(xv.w, w3.w, ac->w);
        }
    }
    __syncthreads();  // all reads of xs4/ws4 done

    // write h3 back into xs4; reload ws4 with W1
    {
        float4 bb = ((const float4*)b)[tc4];
        float4 accs[4] = {ac0, ac1, ac2, ac3};
#pragma unroll
        for (int i = 0; i < 4; i++) {
            float4 o;
            o.x = fmaxf(accs[i].x + bb.x, 0.0f);
            o.y = fmaxf(accs[i].y + bb.y, 0.0f);
            o.z = fmaxf(accs[i].z + bb.z, 0.0f);
            o.w = fmaxf(accs[i].w + bb.w, 0.0f);
            xs4[tn + i][tc4] = o;
        }
    }
    for (int i = tid; i < 1024; i += 256)
        ws4[i >> 4][i & 15] = ((const float4*)W1)[i];
    __syncthreads();

    // ---- stage 2: h4 tile ----
    float4 bc0 = {0,0,0,0}, bc1 = {0,0,0,0}, bc2 = {0,0,0,0}, bc3 = {0,0,0,0};
#pragma unroll 4
    for (int k4 = 0; k4 < 16; k4++) {
        float4 w0 = ws4[k4 * 4 + 0][tc4];
        float4 w1 = ws4[k4 * 4 + 1][tc4];
        float4 w2 = ws4[k4 * 4 + 2][tc4];
        float4 w3 = ws4[k4 * 4 + 3][tc4];
#pragma unroll
        for (int i = 0; i < 4; i++) {
            float4 xv = xs4[tn + i][k4];
            float4* ac = (i == 0) ? &bc0 : (i == 1) ? &bc1 : (i == 2) ? &bc2 : &bc3;
            ac->x = fmaf(xv.x, w0.x, ac->x); ac->y = fmaf(xv.x, w0.y, ac->y);
            ac->z = fmaf(xv.x, w0.z, ac->z); ac->w = fmaf(xv.x, w0.w, ac->w);
            ac->x = fmaf(xv.y, w1.x, ac->x); ac->y = fmaf(xv.y, w1.y, ac->y);
            ac->z = fmaf(xv.y, w1.z, ac->z); ac->w = fmaf(xv.y, w1.w, ac->w);
            ac->x = fmaf(xv.z, w2.x, ac->x); ac->y = fmaf(xv.z, w2.y, ac->y);
            ac->z = fmaf(xv.z, w2.z, ac->z); ac->w = fmaf(xv.z, w2.w, ac->w);
            ac->x = fmaf(xv.w, w3.x, ac->x); ac->y = fmaf(xv.w, w3.y, ac->y);
            ac->z = fmaf(xv.w, w3.z, ac->z); ac->w = fmaf(xv.w, w3.w, ac->w);
        }
    }

    // h4 -> relu -> dot W2 -> reduce over the 16 col-groups (consecutive lanes)
    float4 b1v = ((const float4*)b1)[tc4];
    float4 w2v = ((const float4*)W2)[tc4];
    float b2v  = b2[0];
    float4 bcs[4] = {bc0, bc1, bc2, bc3};
#pragma unroll
    for (int i = 0; i < 4; i++) {
        float s = fmaxf(bcs[i].x + b1v.x, 0.0f) * w2v.x
                + fmaxf(bcs[i].y + b1v.y, 0.0f) * w2v.y
                + fmaxf(bcs[i].z + b1v.z, 0.0f) * w2v.z
                + fmaxf(bcs[i].w + b1v.w, 0.0f) * w2v.w;
        s += __shfl_xor(s, 1);
        s += __shfl_xor(s, 2);
        s += __shfl_xor(s, 4);
        s += __shfl_xor(s, 8);
        int row = node0 + tn + i;
        if (tc4 == 0 && row < n) out[row] = s + b2v;
    }
}

extern "C" void kernel_launch(void* const* d_in, const int* in_sizes, int n_in,
                              void* d_out, int out_size, void* d_ws, size_t ws_size,
                              hipStream_t stream) {
    const float* x_cont = (const float*)d_in[0];
    const int*   ftyp   = (const int*)d_in[1];
    const int*   eidx   = (const int*)d_in[2];
    const float* emb    = (const float*)d_in[3];
    const float* W_in   = (const float*)d_in[4];
    const float* b_in   = (const float*)d_in[5];
    const float* W_g    = (const float*)d_in[6];
    const float* b_g    = (const float*)d_in[7];
    const float* W_o1   = (const float*)d_in[8];
    const float* b_o1   = (const float*)d_in[9];
    const float* W_o2   = (const float*)d_in[10];
    const float* b_o2   = (const float*)d_in[11];
    float* out = (float*)d_out;

    const int n = in_sizes[1];
    const int E = in_sizes[2] / 2;
    const int* src = eidx;
    const int* dst = eidx + E;

    char* p = (char*)d_ws;
    auto alloc = [&](size_t bytes) {
        char* r = p;
        p += (bytes + 255) & ~(size_t)255;
        return r;
    };
    int*   deg    = (int*)  alloc((size_t)n * 4);
    float* disq   = (float*)alloc((size_t)n * 4);
    int*   rowst  = (int*)  alloc((size_t)n * 4);
    int*   cursor = (int*)  alloc((size_t)n * 4);
    int*   bsum   = (int*)  alloc(4096);
    int2*  csr    = (int2*) alloc((size_t)E * 8);
    float* xb     = (float*)alloc((size_t)n * HD * 4);
    float* xo     = (float*)alloc((size_t)n * HD * 4);

    hipMemsetAsync(deg, 0, (size_t)n * 4, stream);

    dim3 blk(256);
    const int nb1   = (n + 255) / 256;
    const int nb_e  = 2048;
    const int nb_nw = (n + 3) / 4;       // one wave per node
    const int nb_t  = (n + 63) / 64;     // 64-node tiles

    k_deg_count<<<nb_e, blk, 0, stream>>>(dst, deg, E);
    k_scan1<<<nb1, blk, 0, stream>>>(deg, rowst, bsum, disq, n);
    k_scan2<<<1, 1024, 0, stream>>>(bsum, nb1);
    k_scan3<<<512, blk, 0, stream>>>(rowst, bsum, cursor, n);
    k_scatter<<<nb_e, blk, 0, stream>>>(src, dst, disq, cursor, csr, E);
    k_input<<<nb_nw, blk, 0, stream>>>(x_cont, ftyp, emb, W_in, b_in, xb, n);

    float* a = xb;
    float* bpp = xo;
    for (int L = 0; L < 2; L++) {
        k_agg<<<nb_nw, blk, 0, stream>>>(a, csr, rowst, deg, disq, bpp, n);
        k_mm<<<nb_t, blk, 0, stream>>>(bpp, W_g + (size_t)L * HD * HD,
                                       b_g + (size_t)L * HD, n);
        float* t = a; a = bpp; bpp = t;
    }
    // layer 3 aggregation, then fused matmul + head
    k_agg<<<nb_nw, blk, 0, stream>>>(a, csr, rowst, deg, disq, bpp, n);
    k_mm_head<<<nb_t, blk, 0, stream>>>(bpp, W_g + (size_t)2 * HD * HD,
                                        b_g + (size_t)2 * HD,
                                        W_o1, b_o1, W_o2, b_o2, out, n);
}

// Round 6
// 404.733 us; speedup vs baseline: 4.4060x; 1.0756x over previous
//
#include <hip/hip_runtime.h>

#define HD 64
#define FC 16
#define FEMB 8

// ---- degree count: int4 edge reads, 4 fire-and-forget atomics per iter ----
__global__ void k_deg_count(const int* __restrict__ dst, int* __restrict__ deg, int E) {
    int t = blockIdx.x * blockDim.x + threadIdx.x;
    int stride = gridDim.x * blockDim.x;
    int nv = E >> 2;
    for (int i = t; i < nv; i += stride) {
        int4 d = ((const int4*)dst)[i];
        atomicAdd(&deg[d.x], 1);
        atomicAdd(&deg[d.y], 1);
        atomicAdd(&deg[d.z], 1);
        atomicAdd(&deg[d.w], 1);
    }
    for (int i = (nv << 2) + t; i < E; i += stride)
        atomicAdd(&deg[dst[i]], 1);
}

// ---- scan phase 1: per-block exclusive scan of deg; also compute disq ----
__global__ void k_scan1(const int* __restrict__ deg, int* __restrict__ row_part,
                        int* __restrict__ bsum, float* __restrict__ disq, int n) {
    __shared__ int s[256];
    int t = threadIdx.x;
    int i = blockIdx.x * 256 + t;
    int v = (i < n) ? deg[i] : 0;
    if (i < n) disq[i] = rsqrtf(1.0f + (float)v);
    s[t] = v;
    __syncthreads();
    for (int off = 1; off < 256; off <<= 1) {
        int a = (t >= off) ? s[t - off] : 0;
        __syncthreads();
        s[t] += a;
        __syncthreads();
    }
    if (i < n) row_part[i] = s[t] - v;
    if (t == 255) bsum[blockIdx.x] = s[255];
}

// ---- scan phase 2: exclusive scan of block sums (single block) ----
__global__ void k_scan2(int* __restrict__ bsum, int nb) {
    __shared__ int s[1024];
    int t = threadIdx.x;
    int v = (t < nb) ? bsum[t] : 0;
    s[t] = v;
    __syncthreads();
    for (int off = 1; off < 1024; off <<= 1) {
        int a = (t >= off) ? s[t - off] : 0;
        __syncthreads();
        s[t] += a;
        __syncthreads();
    }
    if (t < nb) bsum[t] = s[t] - v;
}

// ---- scan phase 3: add block offsets; init cursor copy ----
__global__ void k_scan3(int* __restrict__ row_part, const int* __restrict__ bsum,
                        int* __restrict__ cursor, int n) {
    int stride = gridDim.x * blockDim.x;
    for (int i = blockIdx.x * blockDim.x + threadIdx.x; i < n; i += stride) {
        int rs = row_part[i] + bsum[i >> 8];
        row_part[i] = rs;
        cursor[i] = rs;
    }
}

// ---- scatter: 8 edges per thread, 8 independent atomics in flight ----
__global__ void k_scatter(const int* __restrict__ src, const int* __restrict__ dst,
                          int* __restrict__ cursor, int* __restrict__ csr, int E) {
    int t = blockIdx.x * blockDim.x + threadIdx.x;
    int base = t * 8;
    if (base + 8 <= E) {
        int4 sa = *(const int4*)(src + base);
        int4 sb = *(const int4*)(src + base + 4);
        int4 da = *(const int4*)(dst + base);
        int4 db = *(const int4*)(dst + base + 4);
        int p0 = atomicAdd(&cursor[da.x], 1);
        int p1 = atomicAdd(&cursor[da.y], 1);
        int p2 = atomicAdd(&cursor[da.z], 1);
        int p3 = atomicAdd(&cursor[da.w], 1);
        int p4 = atomicAdd(&cursor[db.x], 1);
        int p5 = atomicAdd(&cursor[db.y], 1);
        int p6 = atomicAdd(&cursor[db.z], 1);
        int p7 = atomicAdd(&cursor[db.w], 1);
        csr[p0] = sa.x; csr[p1] = sa.y; csr[p2] = sa.z; csr[p3] = sa.w;
        csr[p4] = sb.x; csr[p5] = sb.y; csr[p6] = sb.z; csr[p7] = sb.w;
    } else {
        for (int e = base; e < E; e++) {
            int pos = atomicAdd(&cursor[dst[e]], 1);
            csr[pos] = src[e];
        }
    }
}

// ---- input layer: y0 = disq * relu(concat(x_cont, emb[ft]) @ W_in + b_in) ----
__global__ void k_input(const float* __restrict__ xc, const int* __restrict__ ft,
                        const float* __restrict__ emb, const float* __restrict__ Win,
                        const float* __restrict__ bin, const float* __restrict__ disq,
                        float* __restrict__ y, int n) {
    int lane = threadIdx.x & 63;
    int wid  = (blockIdx.x * blockDim.x + threadIdx.x) >> 6;
    if (wid >= n) return;
    float acc = bin[lane];
    const float* xr = xc + (size_t)wid * FC;
#pragma unroll
    for (int k = 0; k < FC; k++)
        acc = fmaf(xr[k], Win[k * HD + lane], acc);
    int t = ft[wid];
    const float* er = emb + (size_t)t * FEMB;
#pragma unroll
    for (int k = 0; k < FEMB; k++)
        acc = fmaf(er[k], Win[(FC + k) * HD + lane], acc);
    y[(size_t)wid * HD + lane] = fmaxf(acc, 0.0f) * disq[wid];
}

// ---- aggregation: agg_i = disq_i * (y_i + sum_{j in N(i)} y_j) ----
// one wave per node, masked 8-wide weight-free gather rounds
__global__ void k_agg(const float* __restrict__ y, const int* __restrict__ csr,
                      const int* __restrict__ rs, const int* __restrict__ deg,
                      const float* __restrict__ disq, float* __restrict__ agg, int n) {
    int lane = threadIdx.x & 63;
    int node = (blockIdx.x * blockDim.x + threadIdx.x) >> 6;
    if (node >= n) return;
    int j   = rs[node];
    int end = j + deg[node];
    float di = disq[node];
    float a0 = 0.f, a1 = 0.f, a2 = 0.f, a3 = 0.f;
    float a4 = 0.f, a5 = 0.f, a6 = 0.f, a7 = 0.f;
    for (; j < end; j += 8) {
        int i1 = j + 1, i2 = j + 2, i3 = j + 3;
        int i4 = j + 4, i5 = j + 5, i6 = j + 6, i7 = j + 7;
        int s0 = csr[j];
        int s1 = csr[i1 < end ? i1 : j];
        int s2 = csr[i2 < end ? i2 : j];
        int s3 = csr[i3 < end ? i3 : j];
        int s4 = csr[i4 < end ? i4 : j];
        int s5 = csr[i5 < end ? i5 : j];
        int s6 = csr[i6 < end ? i6 : j];
        int s7 = csr[i7 < end ? i7 : j];
        float v0 = y[(size_t)s0 * HD + lane];
        float v1 = y[(size_t)s1 * HD + lane];
        float v2 = y[(size_t)s2 * HD + lane];
        float v3 = y[(size_t)s3 * HD + lane];
        float v4 = y[(size_t)s4 * HD + lane];
        float v5 = y[(size_t)s5 * HD + lane];
        float v6 = y[(size_t)s6 * HD + lane];
        float v7 = y[(size_t)s7 * HD + lane];
        a0 += v0;
        a1 += (i1 < end) ? v1 : 0.f;
        a2 += (i2 < end) ? v2 : 0.f;
        a3 += (i3 < end) ? v3 : 0.f;
        a4 += (i4 < end) ? v4 : 0.f;
        a5 += (i5 < end) ? v5 : 0.f;
        a6 += (i6 < end) ? v6 : 0.f;
        a7 += (i7 < end) ? v7 : 0.f;
    }
    float acc = ((a0 + a1) + (a2 + a3)) + ((a4 + a5) + (a6 + a7));
    agg[(size_t)node * HD + lane] = di * (acc + y[(size_t)node * HD + lane]);
}

// ---- tiled matmul, IN PLACE: x[tile] = disq * relu(x[tile] @ W + b) ----
__global__ __launch_bounds__(256, 4)
void k_mm(float* __restrict__ x, const float* __restrict__ W,
          const float* __restrict__ b, const float* __restrict__ disq, int n) {
    __shared__ float4 ws4[64][16];  // ws4[k][c4]
    __shared__ float4 xs4[64][17];  // xs4[nn][k4], padded
    int tid = threadIdx.x;
    int node0 = blockIdx.x * 64;

    for (int i = tid; i < 1024; i += 256)
        ws4[i >> 4][i & 15] = ((const float4*)W)[i];
    for (int i = tid; i < 1024; i += 256) {
        int nn = i >> 4, k4 = i & 15;
        int row = node0 + nn; if (row >= n) row = n - 1;
        xs4[nn][k4] = ((const float4*)(x + (size_t)row * HD))[k4];
    }
    __syncthreads();

    int tc4 = tid & 15;
    int tn  = (tid >> 4) * 4;
    float4 ac0 = {0,0,0,0}, ac1 = {0,0,0,0}, ac2 = {0,0,0,0}, ac3 = {0,0,0,0};

#pragma unroll 4
    for (int k4 = 0; k4 < 16; k4++) {
        float4 w0 = ws4[k4 * 4 + 0][tc4];
        float4 w1 = ws4[k4 * 4 + 1][tc4];
        float4 w2 = ws4[k4 * 4 + 2][tc4];
        float4 w3 = ws4[k4 * 4 + 3][tc4];
#pragma unroll
        for (int i = 0; i < 4; i++) {
            float4 xv = xs4[tn + i][k4];
            float4* ac = (i == 0) ? &ac0 : (i == 1) ? &ac1 : (i == 2) ? &ac2 : &ac3;
            ac->x = fmaf(xv.x, w0.x, ac->x); ac->y = fmaf(xv.x, w0.y, ac->y);
            ac->z = fmaf(xv.x, w0.z, ac->z); ac->w = fmaf(xv.x, w0.w, ac->w);
            ac->x = fmaf(xv.y, w1.x, ac->x); ac->y = fmaf(xv.y, w1.y, ac->y);
            ac->z = fmaf(xv.y, w1.z, ac->z); ac->w = fmaf(xv.y, w1.w, ac->w);
            ac->x = fmaf(xv.z, w2.x, ac->x); ac->y = fmaf(xv.z, w2.y, ac->y);
            ac->z = fmaf(xv.z, w2.z, ac->z); ac->w = fmaf(xv.z, w2.w, ac->w);
            ac->x = fmaf(xv.w, w3.x, ac->x); ac->y = fmaf(xv.w, w3.y, ac->y);
            ac->z = fmaf(xv.w, w3.z, ac->z); ac->w = fmaf(xv.w, w3.w, ac->w);
        }
    }

    float4 bb = ((const float4*)b)[tc4];
    float4 accs[4] = {ac0, ac1, ac2, ac3};
#pragma unroll
    for (int i = 0; i < 4; i++) {
        int row = node0 + tn + i;
        if (row < n) {
            float dq = disq[row];
            float4 o;
            o.x = fmaxf(accs[i].x + bb.x, 0.0f) * dq;
            o.y = fmaxf(accs[i].y + bb.y, 0.0f) * dq;
            o.z = fmaxf(accs[i].z + bb.z, 0.0f) * dq;
            o.w = fmaxf(accs[i].w + bb.w, 0.0f) * dq;
            *(float4*)(x + (size_t)row * HD + tc4 * 4) = o;
        }
    }
}

// ---- fused layer-3 matmul + head (input agg, NO output scaling) ----
__global__ __launch_bounds__(256, 4)
void k_mm_head(const float* __restrict__ x, const float* __restrict__ W,
               const float* __restrict__ b, const float* __restrict__ W1,
               const float* __restrict__ b1, const float* __restrict__ W2,
               const float* __restrict__ b2, float* __restrict__ out, int n) {
    __shared__ float4 ws4[64][16];
    __shared__ float4 xs4[64][17];
    int tid = threadIdx.x;
    int node0 = blockIdx.x * 64;

    for (int i = tid; i < 1024; i += 256)
        ws4[i >> 4][i & 15] = ((const float4*)W)[i];
    for (int i = tid; i < 1024; i += 256) {
        int nn = i >> 4, k4 = i & 15;
        int row = node0 + nn; if (row >= n) row = n - 1;
        xs4[nn][k4] = ((const float4*)(x + (size_t)row * HD))[k4];
    }
    __syncthreads();

    int tc4 = tid & 15;
    int tn  = (tid >> 4) * 4;

    float4 ac0 = {0,0,0,0}, ac1 = {0,0,0,0}, ac2 = {0,0,0,0}, ac3 = {0,0,0,0};
#pragma unroll 4
    for (int k4 = 0; k4 < 16; k4++) {
        float4 w0 = ws4[k4 * 4 + 0][tc4];
        float4 w1 = ws4[k4 * 4 + 1][tc4];
        float4 w2 = ws4[k4 * 4 + 2][tc4];
        float4 w3 = ws4[k4 * 4 + 3][tc4];
#pragma unroll
        for (int i = 0; i < 4; i++) {
            float4 xv = xs4[tn + i][k4];
            float4* ac = (i == 0) ? &ac0 : (i == 1) ? &ac1 : (i == 2) ? &ac2 : &ac3;
            ac->x = fmaf(xv.x, w0.x, ac->x); ac->y = fmaf(xv.x, w0.y, ac->y);
            ac->z = fmaf(xv.x, w0.z, ac->z); ac->w = fmaf(xv.x, w0.w, ac->w);
            ac->x = fmaf(xv.y, w1.x, ac->x); ac->y = fmaf(xv.y, w1.y, ac->y);
            ac->z = fmaf(xv.y, w1.z, ac->z); ac->w = fmaf(xv.y, w1.w, ac->w);
            ac->x = fmaf(xv.z, w2.x, ac->x); ac->y = fmaf(xv.z, w2.y, ac->y);
            ac->z = fmaf(xv.z, w2.z, ac->z); ac->w = fmaf(xv.z, w2.w, ac->w);
            ac->x = fmaf(xv.w, w3.x, ac->x); ac->y = fmaf(xv.w, w3.y, ac->y);
            ac->z = fmaf(xv.w, w3.z, ac->z); ac->w = fmaf(xv.w, w3.w, ac->w);
        }
    }
    __syncthreads();

    {
        float4 bb = ((const float4*)b)[tc4];
        float4 accs[4] = {ac0, ac1, ac2, ac3};
#pragma unroll
        for (int i = 0; i < 4; i++) {
            float4 o;
            o.x = fmaxf(accs[i].x + bb.x, 0.0f);
            o.y = fmaxf(accs[i].y + bb.y, 0.0f);
            o.z = fmaxf(accs[i].z + bb.z, 0.0f);
            o.w = fmaxf(accs[i].w + bb.w, 0.0f);
            xs4[tn + i][tc4] = o;
        }
    }
    for (int i = tid; i < 1024; i += 256)
        ws4[i >> 4][i & 15] = ((const float4*)W1)[i];
    __syncthreads();

    float4 bc0 = {0,0,0,0}, bc1 = {0,0,0,0}, bc2 = {0,0,0,0}, bc3 = {0,0,0,0};
#pragma unroll 4
    for (int k4 = 0; k4 < 16; k4++) {
        float4 w0 = ws4[k4 * 4 + 0][tc4];
        float4 w1 = ws4[k4 * 4 + 1][tc4];
        float4 w2 = ws4[k4 * 4 + 2][tc4];
        float4 w3 = ws4[k4 * 4 + 3][tc4];
#pragma unroll
        for (int i = 0; i < 4; i++) {
            float4 xv = xs4[tn + i][k4];
            float4* ac = (i == 0) ? &bc0 : (i == 1) ? &bc1 : (i == 2) ? &bc2 : &bc3;
            ac->x = fmaf(xv.x, w0.x, ac->x); ac->y = fmaf(xv.x, w0.y, ac->y);
            ac->z = fmaf(xv.x, w0.z, ac->z); ac->w = fmaf(xv.x, w0.w, ac->w);
            ac->x = fmaf(xv.y, w1.x, ac->x); ac->y = fmaf(xv.y, w1.y, ac->y);
            ac->z = fmaf(xv.y, w1.z, ac->z); ac->w = fmaf(xv.y, w1.w, ac->w);
            ac->x = fmaf(xv.z, w2.x, ac->x); ac->y = fmaf(xv.z, w2.y, ac->y);
            ac->z = fmaf(xv.z, w2.z, ac->z); ac->w = fmaf(xv.z, w2.w, ac->w);
            ac->x = fmaf(xv.w, w3.x, ac->x); ac->y = fmaf(xv.w, w3.y, ac->y);
            ac->z = fmaf(xv.w, w3.z, ac->z); ac->w = fmaf(xv.w, w3.w, ac->w);
        }
    }

    float4 b1v = ((const float4*)b1)[tc4];
    float4 w2v = ((const float4*)W2)[tc4];
    float b2v  = b2[0];
    float4 bcs[4] = {bc0, bc1, bc2, bc3};
#pragma unroll
    for (int i = 0; i < 4; i++) {
        float s = fmaxf(bcs[i].x + b1v.x, 0.0f) * w2v.x
                + fmaxf(bcs[i].y + b1v.y, 0.0f) * w2v.y
                + fmaxf(bcs[i].z + b1v.z, 0.0f) * w2v.z
                + fmaxf(bcs[i].w + b1v.w, 0.0f) * w2v.w;
        s += __shfl_xor(s, 1);
        s += __shfl_xor(s, 2);
        s += __shfl_xor(s, 4);
        s += __shfl_xor(s, 8);
        int row = node0 + tn + i;
        if (tc4 == 0 && row < n) out[row] = s + b2v;
    }
}

extern "C" void kernel_launch(void* const* d_in, const int* in_sizes, int n_in,
                              void* d_out, int out_size, void* d_ws, size_t ws_size,
                              hipStream_t stream) {
    const float* x_cont = (const float*)d_in[0];
    const int*   ftyp   = (const int*)d_in[1];
    const int*   eidx   = (const int*)d_in[2];
    const float* emb    = (const float*)d_in[3];
    const float* W_in   = (const float*)d_in[4];
    const float* b_in   = (const float*)d_in[5];
    const float* W_g    = (const float*)d_in[6];
    const float* b_g    = (const float*)d_in[7];
    const float* W_o1   = (const float*)d_in[8];
    const float* b_o1   = (const float*)d_in[9];
    const float* W_o2   = (const float*)d_in[10];
    const float* b_o2   = (const float*)d_in[11];
    float* out = (float*)d_out;

    const int n = in_sizes[1];
    const int E = in_sizes[2] / 2;
    const int* src = eidx;
    const int* dst = eidx + E;

    char* p = (char*)d_ws;
    auto alloc = [&](size_t bytes) {
        char* r = p;
        p += (bytes + 255) & ~(size_t)255;
        return r;
    };
    int*   deg    = (int*)  alloc((size_t)n * 4);
    float* disq   = (float*)alloc((size_t)n * 4);
    int*   rowst  = (int*)  alloc((size_t)n * 4);
    int*   cursor = (int*)  alloc((size_t)n * 4);
    int*   bsum   = (int*)  alloc(4096);
    int*   csr    = (int*)  alloc((size_t)E * 4);
    float* xb     = (float*)alloc((size_t)n * HD * 4);
    float* xo     = (float*)alloc((size_t)n * HD * 4);

    hipMemsetAsync(deg, 0, (size_t)n * 4, stream);

    dim3 blk(256);
    const int nb1   = (n + 255) / 256;
    const int nb_nw = (n + 3) / 4;            // one wave per node
    const int nb_t  = (n + 63) / 64;          // 64-node tiles
    const int nb_s  = (E / 8 + 255) / 256;    // 8 edges per thread

    k_deg_count<<<1024, blk, 0, stream>>>(dst, deg, E);
    k_scan1<<<nb1, blk, 0, stream>>>(deg, rowst, bsum, disq, n);
    k_scan2<<<1, 1024, 0, stream>>>(bsum, nb1);
    k_scan3<<<512, blk, 0, stream>>>(rowst, bsum, cursor, n);
    k_scatter<<<nb_s, blk, 0, stream>>>(src, dst, cursor, csr, E);
    k_input<<<nb_nw, blk, 0, stream>>>(x_cont, ftyp, emb, W_in, b_in, disq, xb, n);

    float* a = xb;
    float* bpp = xo;
    for (int L = 0; L < 2; L++) {
        k_agg<<<nb_nw, blk, 0, stream>>>(a, csr, rowst, deg, disq, bpp, n);
        k_mm<<<nb_t, blk, 0, stream>>>(bpp, W_g + (size_t)L * HD * HD,
                                       b_g + (size_t)L * HD, disq, n);
        float* t = a; a = bpp; bpp = t;
    }
    k_agg<<<nb_nw, blk, 0, stream>>>(a, csr, rowst, deg, disq, bpp, n);
    k_mm_head<<<nb_t, blk, 0, stream>>>(bpp, W_g + (size_t)2 * HD * HD,
                                        b_g + (size_t)2 * HD,
                                        W_o1, b_o1, W_o2, b_o2, out, n);
}

// Round 7
// 367.512 us; speedup vs baseline: 4.8523x; 1.1013x over previous
//
#include <hip/hip_runtime.h>

#define HD 64
#define FC 16
#define FEMB 8

// ---- pass 1: count + rank. rank[e] = running index of e within dst bucket ----
__global__ void k_count_rank(const int* __restrict__ dst, int* __restrict__ cnt,
                             int* __restrict__ rank, int E) {
    int e = blockIdx.x * blockDim.x + threadIdx.x;
    if (e >= E) return;
    rank[e] = atomicAdd(&cnt[dst[e]], 1);
}

// ---- scan phase 1: per-block exclusive scan of cnt; also compute disq ----
__global__ void k_scan1(const int* __restrict__ cnt, int* __restrict__ row_part,
                        int* __restrict__ bsum, float* __restrict__ disq, int n) {
    __shared__ int s[256];
    int t = threadIdx.x;
    int i = blockIdx.x * 256 + t;
    int v = (i < n) ? cnt[i] : 0;
    if (i < n) disq[i] = rsqrtf(1.0f + (float)v);
    s[t] = v;
    __syncthreads();
    for (int off = 1; off < 256; off <<= 1) {
        int a = (t >= off) ? s[t - off] : 0;
        __syncthreads();
        s[t] += a;
        __syncthreads();
    }
    if (i < n) row_part[i] = s[t] - v;
    if (t == 255) bsum[blockIdx.x] = s[255];
}

// ---- scan phase 2: exclusive scan of block sums (single block) ----
__global__ void k_scan2(int* __restrict__ bsum, int nb) {
    __shared__ int s[1024];
    int t = threadIdx.x;
    int v = (t < nb) ? bsum[t] : 0;
    s[t] = v;
    __syncthreads();
    for (int off = 1; off < 1024; off <<= 1) {
        int a = (t >= off) ? s[t - off] : 0;
        __syncthreads();
        s[t] += a;
        __syncthreads();
    }
    if (t < nb) bsum[t] = s[t] - v;
}

// ---- scan phase 3: add block offsets ----
__global__ void k_scan3(int* __restrict__ row_part, const int* __restrict__ bsum, int n) {
    int stride = gridDim.x * blockDim.x;
    for (int i = blockIdx.x * blockDim.x + threadIdx.x; i < n; i += stride)
        row_part[i] += bsum[i >> 8];
}

// ---- pass 2: reorder. All reads coalesced; one fire-and-forget random store ----
__global__ void k_reorder(const int* __restrict__ src, const int* __restrict__ dst,
                          const int* __restrict__ rank, const int* __restrict__ rowst,
                          int* __restrict__ csr, int E) {
    int e = blockIdx.x * blockDim.x + threadIdx.x;
    if (e >= E) return;
    csr[rowst[dst[e]] + rank[e]] = src[e];
}

// ---- input layer: y0 = disq * relu(concat(x_cont, emb[ft]) @ W_in + b_in) ----
__global__ void k_input(const float* __restrict__ xc, const int* __restrict__ ft,
                        const float* __restrict__ emb, const float* __restrict__ Win,
                        const float* __restrict__ bin, const float* __restrict__ disq,
                        float* __restrict__ y, int n) {
    int lane = threadIdx.x & 63;
    int wid  = (blockIdx.x * blockDim.x + threadIdx.x) >> 6;
    if (wid >= n) return;
    float acc = bin[lane];
    const float* xr = xc + (size_t)wid * FC;
#pragma unroll
    for (int k = 0; k < FC; k++)
        acc = fmaf(xr[k], Win[k * HD + lane], acc);
    int t = ft[wid];
    const float* er = emb + (size_t)t * FEMB;
#pragma unroll
    for (int k = 0; k < FEMB; k++)
        acc = fmaf(er[k], Win[(FC + k) * HD + lane], acc);
    y[(size_t)wid * HD + lane] = fmaxf(acc, 0.0f) * disq[wid];
}

// ---- aggregation: agg_i = disq_i * (y_i + sum_{j in N(i)} y_j) ----
// wave per node; float4 lanes: group g=lane>>4 picks edge slot, c4=lane&15 picks cols.
// Each load instruction covers 4 edges x 16B = 1KB. 16 edges per chunk.
__global__ void k_agg(const float4* __restrict__ y4, const int* __restrict__ csr,
                      const int* __restrict__ rs, const int* __restrict__ deg,
                      const float* __restrict__ disq, float4* __restrict__ agg4, int n) {
    int lane = threadIdx.x & 63;
    int node = (blockIdx.x * blockDim.x + threadIdx.x) >> 6;
    if (node >= n) return;
    int g  = lane >> 4;
    int c4 = lane & 15;
    int start = rs[node];
    int end   = start + deg[node];
    float4 acc = {0, 0, 0, 0};
    for (int j = start; j < end; j += 16) {
#pragma unroll
        for (int slot = 0; slot < 4; slot++) {
            int e = j + slot * 4 + g;
            bool ok = e < end;
            int ec = ok ? e : j;              // clamp: duplicate lines, HW-coalesced
            int s = csr[ec];
            float4 v = y4[(size_t)s * 16 + c4];
            if (ok) {
                acc.x += v.x; acc.y += v.y; acc.z += v.z; acc.w += v.w;
            }
        }
    }
    // reduce the 4 edge-groups (lane bits 4 and 5)
    acc.x += __shfl_xor(acc.x, 16); acc.y += __shfl_xor(acc.y, 16);
    acc.z += __shfl_xor(acc.z, 16); acc.w += __shfl_xor(acc.w, 16);
    acc.x += __shfl_xor(acc.x, 32); acc.y += __shfl_xor(acc.y, 32);
    acc.z += __shfl_xor(acc.z, 32); acc.w += __shfl_xor(acc.w, 32);
    if (g == 0) {
        float4 self = y4[(size_t)node * 16 + c4];
        float di = disq[node];
        float4 o;
        o.x = di * (acc.x + self.x);
        o.y = di * (acc.y + self.y);
        o.z = di * (acc.z + self.z);
        o.w = di * (acc.w + self.w);
        agg4[(size_t)node * 16 + c4] = o;
    }
}

// ---- tiled matmul, IN PLACE: x[tile] = disq * relu(x[tile] @ W + b) ----
__global__ __launch_bounds__(256, 4)
void k_mm(float* __restrict__ x, const float* __restrict__ W,
          const float* __restrict__ b, const float* __restrict__ disq, int n) {
    __shared__ float4 ws4[64][16];
    __shared__ float4 xs4[64][17];
    int tid = threadIdx.x;
    int node0 = blockIdx.x * 64;

    for (int i = tid; i < 1024; i += 256)
        ws4[i >> 4][i & 15] = ((const float4*)W)[i];
    for (int i = tid; i < 1024; i += 256) {
        int nn = i >> 4, k4 = i & 15;
        int row = node0 + nn; if (row >= n) row = n - 1;
        xs4[nn][k4] = ((const float4*)(x + (size_t)row * HD))[k4];
    }
    __syncthreads();

    int tc4 = tid & 15;
    int tn  = (tid >> 4) * 4;
    float4 ac0 = {0,0,0,0}, ac1 = {0,0,0,0}, ac2 = {0,0,0,0}, ac3 = {0,0,0,0};

#pragma unroll 4
    for (int k4 = 0; k4 < 16; k4++) {
        float4 w0 = ws4[k4 * 4 + 0][tc4];
        float4 w1 = ws4[k4 * 4 + 1][tc4];
        float4 w2 = ws4[k4 * 4 + 2][tc4];
        float4 w3 = ws4[k4 * 4 + 3][tc4];
#pragma unroll
        for (int i = 0; i < 4; i++) {
            float4 xv = xs4[tn + i][k4];
            float4* ac = (i == 0) ? &ac0 : (i == 1) ? &ac1 : (i == 2) ? &ac2 : &ac3;
            ac->x = fmaf(xv.x, w0.x, ac->x); ac->y = fmaf(xv.x, w0.y, ac->y);
            ac->z = fmaf(xv.x, w0.z, ac->z); ac->w = fmaf(xv.x, w0.w, ac->w);
            ac->x = fmaf(xv.y, w1.x, ac->x); ac->y = fmaf(xv.y, w1.y, ac->y);
            ac->z = fmaf(xv.y, w1.z, ac->z); ac->w = fmaf(xv.y, w1.w, ac->w);
            ac->x = fmaf(xv.z, w2.x, ac->x); ac->y = fmaf(xv.z, w2.y, ac->y);
            ac->z = fmaf(xv.z, w2.z, ac->z); ac->w = fmaf(xv.z, w2.w, ac->w);
            ac->x = fmaf(xv.w, w3.x, ac->x); ac->y = fmaf(xv.w, w3.y, ac->y);
            ac->z = fmaf(xv.w, w3.z, ac->z); ac->w = fmaf(xv.w, w3.w, ac->w);
        }
    }

    float4 bb = ((const float4*)b)[tc4];
    float4 accs[4] = {ac0, ac1, ac2, ac3};
#pragma unroll
    for (int i = 0; i < 4; i++) {
        int row = node0 + tn + i;
        if (row < n) {
            float dq = disq[row];
            float4 o;
            o.x = fmaxf(accs[i].x + bb.x, 0.0f) * dq;
            o.y = fmaxf(accs[i].y + bb.y, 0.0f) * dq;
            o.z = fmaxf(accs[i].z + bb.z, 0.0f) * dq;
            o.w = fmaxf(accs[i].w + bb.w, 0.0f) * dq;
            *(float4*)(x + (size_t)row * HD + tc4 * 4) = o;
        }
    }
}

// ---- fused layer-3 matmul + head ----
__global__ __launch_bounds__(256, 4)
void k_mm_head(const float* __restrict__ x, const float* __restrict__ W,
               const float* __restrict__ b, const float* __restrict__ W1,
               const float* __restrict__ b1, const float* __restrict__ W2,
               const float* __restrict__ b2, float* __restrict__ out, int n) {
    __shared__ float4 ws4[64][16];
    __shared__ float4 xs4[64][17];
    int tid = threadIdx.x;
    int node0 = blockIdx.x * 64;

    for (int i = tid; i < 1024; i += 256)
        ws4[i >> 4][i & 15] = ((const float4*)W)[i];
    for (int i = tid; i < 1024; i += 256) {
        int nn = i >> 4, k4 = i & 15;
        int row = node0 + nn; if (row >= n) row = n - 1;
        xs4[nn][k4] = ((const float4*)(x + (size_t)row * HD))[k4];
    }
    __syncthreads();

    int tc4 = tid & 15;
    int tn  = (tid >> 4) * 4;

    float4 ac0 = {0,0,0,0}, ac1 = {0,0,0,0}, ac2 = {0,0,0,0}, ac3 = {0,0,0,0};
#pragma unroll 4
    for (int k4 = 0; k4 < 16; k4++) {
        float4 w0 = ws4[k4 * 4 + 0][tc4];
        float4 w1 = ws4[k4 * 4 + 1][tc4];
        float4 w2 = ws4[k4 * 4 + 2][tc4];
        float4 w3 = ws4[k4 * 4 + 3][tc4];
#pragma unroll
        for (int i = 0; i < 4; i++) {
            float4 xv = xs4[tn + i][k4];
            float4* ac = (i == 0) ? &ac0 : (i == 1) ? &ac1 : (i == 2) ? &ac2 : &ac3;
            ac->x = fmaf(xv.x, w0.x, ac->x); ac->y = fmaf(xv.x, w0.y, ac->y);
            ac->z = fmaf(xv.x, w0.z, ac->z); ac->w = fmaf(xv.x, w0.w, ac->w);
            ac->x = fmaf(xv.y, w1.x, ac->x); ac->y = fmaf(xv.y, w1.y, ac->y);
            ac->z = fmaf(xv.y, w1.z, ac->z); ac->w = fmaf(xv.y, w1.w, ac->w);
            ac->x = fmaf(xv.z, w2.x, ac->x); ac->y = fmaf(xv.z, w2.y, ac->y);
            ac->z = fmaf(xv.z, w2.z, ac->z); ac->w = fmaf(xv.z, w2.w, ac->w);
            ac->x = fmaf(xv.w, w3.x, ac->x); ac->y = fmaf(xv.w, w3.y, ac->y);
            ac->z = fmaf(xv.w, w3.z, ac->z); ac->w = fmaf(xv.w, w3.w, ac->w);
        }
    }
    __syncthreads();

    {
        float4 bb = ((const float4*)b)[tc4];
        float4 accs[4] = {ac0, ac1, ac2, ac3};
#pragma unroll
        for (int i = 0; i < 4; i++) {
            float4 o;
            o.x = fmaxf(accs[i].x + bb.x, 0.0f);
            o.y = fmaxf(accs[i].y + bb.y, 0.0f);
            o.z = fmaxf(accs[i].z + bb.z, 0.0f);
            o.w = fmaxf(accs[i].w + bb.w, 0.0f);
            xs4[tn + i][tc4] = o;
        }
    }
    for (int i = tid; i < 1024; i += 256)
        ws4[i >> 4][i & 15] = ((const float4*)W1)[i];
    __syncthreads();

    float4 bc0 = {0,0,0,0}, bc1 = {0,0,0,0}, bc2 = {0,0,0,0}, bc3 = {0,0,0,0};
#pragma unroll 4
    for (int k4 = 0; k4 < 16; k4++) {
        float4 w0 = ws4[k4 * 4 + 0][tc4];
        float4 w1 = ws4[k4 * 4 + 1][tc4];
        float4 w2 = ws4[k4 * 4 + 2][tc4];
        float4 w3 = ws4[k4 * 4 + 3][tc4];
#pragma unroll
        for (int i = 0; i < 4; i++) {
            float4 xv = xs4[tn + i][k4];
            float4* ac = (i == 0) ? &bc0 : (i == 1) ? &bc1 : (i == 2) ? &bc2 : &bc3;
            ac->x = fmaf(xv.x, w0.x, ac->x); ac->y = fmaf(xv.x, w0.y, ac->y);
            ac->z = fmaf(xv.x, w0.z, ac->z); ac->w = fmaf(xv.x, w0.w, ac->w);
            ac->x = fmaf(xv.y, w1.x, ac->x); ac->y = fmaf(xv.y, w1.y, ac->y);
            ac->z = fmaf(xv.y, w1.z, ac->z); ac->w = fmaf(xv.y, w1.w, ac->w);
            ac->x = fmaf(xv.z, w2.x, ac->x); ac->y = fmaf(xv.z, w2.y, ac->y);
            ac->z = fmaf(xv.z, w2.z, ac->z); ac->w = fmaf(xv.z, w2.w, ac->w);
            ac->x = fmaf(xv.w, w3.x, ac->x); ac->y = fmaf(xv.w, w3.y, ac->y);
            ac->z = fmaf(xv.w, w3.z, ac->z); ac->w = fmaf(xv.w, w3.w, ac->w);
        }
    }

    float4 b1v = ((const float4*)b1)[tc4];
    float4 w2v = ((const float4*)W2)[tc4];
    float b2v  = b2[0];
    float4 bcs[4] = {bc0, bc1, bc2, bc3};
#pragma unroll
    for (int i = 0; i < 4; i++) {
        float s = fmaxf(bcs[i].x + b1v.x, 0.0f) * w2v.x
                + fmaxf(bcs[i].y + b1v.y, 0.0f) * w2v.y
                + fmaxf(bcs[i].z + b1v.z, 0.0f) * w2v.z
                + fmaxf(bcs[i].w + b1v.w, 0.0f) * w2v.w;
        s += __shfl_xor(s, 1);
        s += __shfl_xor(s, 2);
        s += __shfl_xor(s, 4);
        s += __shfl_xor(s, 8);
        int row = node0 + tn + i;
        if (tc4 == 0 && row < n) out[row] = s + b2v;
    }
}

extern "C" void kernel_launch(void* const* d_in, const int* in_sizes, int n_in,
                              void* d_out, int out_size, void* d_ws, size_t ws_size,
                              hipStream_t stream) {
    const float* x_cont = (const float*)d_in[0];
    const int*   ftyp   = (const int*)d_in[1];
    const int*   eidx   = (const int*)d_in[2];
    const float* emb    = (const float*)d_in[3];
    const float* W_in   = (const float*)d_in[4];
    const float* b_in   = (const float*)d_in[5];
    const float* W_g    = (const float*)d_in[6];
    const float* b_g    = (const float*)d_in[7];
    const float* W_o1   = (const float*)d_in[8];
    const float* b_o1   = (const float*)d_in[9];
    const float* W_o2   = (const float*)d_in[10];
    const float* b_o2   = (const float*)d_in[11];
    float* out = (float*)d_out;

    const int n = in_sizes[1];
    const int E = in_sizes[2] / 2;
    const int* src = eidx;
    const int* dst = eidx + E;

    char* p = (char*)d_ws;
    auto alloc = [&](size_t bytes) {
        char* r = p;
        p += (bytes + 255) & ~(size_t)255;
        return r;
    };
    int*   cnt   = (int*)  alloc((size_t)n * 4);
    float* disq  = (float*)alloc((size_t)n * 4);
    int*   rowst = (int*)  alloc((size_t)n * 4);
    int*   bsum  = (int*)  alloc(4096);
    int*   rank  = (int*)  alloc((size_t)E * 4);
    int*   csr   = (int*)  alloc((size_t)E * 4);
    float* xb    = (float*)alloc((size_t)n * HD * 4);
    float* xo    = (float*)alloc((size_t)n * HD * 4);

    hipMemsetAsync(cnt, 0, (size_t)n * 4, stream);

    dim3 blk(256);
    const int nb1   = (n + 255) / 256;
    const int nb_e  = (E + 255) / 256;        // one edge per thread
    const int nb_nw = (n + 3) / 4;            // one wave per node
    const int nb_t  = (n + 63) / 64;          // 64-node tiles

    k_count_rank<<<nb_e, blk, 0, stream>>>(dst, cnt, rank, E);
    k_scan1<<<nb1, blk, 0, stream>>>(cnt, rowst, bsum, disq, n);
    k_scan2<<<1, 1024, 0, stream>>>(bsum, nb1);
    k_scan3<<<512, blk, 0, stream>>>(rowst, bsum, n);
    k_reorder<<<nb_e, blk, 0, stream>>>(src, dst, rank, rowst, csr, E);
    k_input<<<nb_nw, blk, 0, stream>>>(x_cont, ftyp, emb, W_in, b_in, disq, xb, n);

    float* a = xb;
    float* bpp = xo;
    for (int L = 0; L < 2; L++) {
        k_agg<<<nb_nw, blk, 0, stream>>>((const float4*)a, csr, rowst, cnt, disq,
                                         (float4*)bpp, n);
        k_mm<<<nb_t, blk, 0, stream>>>(bpp, W_g + (size_t)L * HD * HD,
                                       b_g + (size_t)L * HD, disq, n);
        float* t = a; a = bpp; bpp = t;
    }
    k_agg<<<nb_nw, blk, 0, stream>>>((const float4*)a, csr, rowst, cnt, disq,
                                     (float4*)bpp, n);
    k_mm_head<<<nb_t, blk, 0, stream>>>(bpp, W_g + (size_t)2 * HD * HD,
                                        b_g + (size_t)2 * HD,
                                        W_o1, b_o1, W_o2, b_o2, out, n);
}